// Round 1
// baseline (32.978 us; speedup 1.0000x reference)
//
#include <hip/hip_runtime.h>

// 3D neighborhood attention, 40^3 grid, NH=8 heads, HD=6, KS=3 (27 neighbors).
// out[c= h*3+o][x][y][z] = (sum_k p_k * off_k[o]) with p = softmax(q.k*scale + rpb)
// OOB neighbors: k zero-padded -> score = rpb only (still in softmax).

#define NHE   8
#define HDIM  6
#define DIMC  48
#define GS    40
#define NVOX  (GS*GS*GS)   // 64000

__global__ __launch_bounds__(256) void natt_kernel(
    const float* __restrict__ q, const float* __restrict__ kk,
    const float* __restrict__ rpb, float* __restrict__ out)
{
    __shared__ float srpb[NHE * 27];
    int t = threadIdx.x;
    if (t < NHE * 27) srpb[t] = rpb[t];
    __syncthreads();

    int tid = blockIdx.x * 256 + t;
    int h   = tid & 7;        // head
    int vox = tid >> 3;       // linear voxel, z fastest
    int z  = vox % GS;
    int xy = vox / GS;
    int y  = xy % GS;
    int x  = xy / GS;

    const float SCALE = 0.4082482904638631f;  // 6^-0.5
    const float* qp = q + vox * DIMC + h * HDIM;
    float q0 = qp[0] * SCALE, q1 = qp[1] * SCALE, q2 = qp[2] * SCALE;
    float q3 = qp[3] * SCALE, q4 = qp[4] * SCALE, q5 = qp[5] * SCALE;

    float sc[27];
    float mx = -1e30f;
    #pragma unroll
    for (int i = 0; i < 3; ++i)
    #pragma unroll
    for (int j = 0; j < 3; ++j)
    #pragma unroll
    for (int l = 0; l < 3; ++l) {
        int xx = x + i - 1, yy = y + j - 1, zz = z + l - 1;
        float dot = 0.0f;
        if (((unsigned)xx < GS) & ((unsigned)yy < GS) & ((unsigned)zz < GS)) {
            const float* kp = kk + ((size_t)(xx * 1600 + yy * 40 + zz) * DIMC + h * HDIM);
            dot = q0 * kp[0] + q1 * kp[1] + q2 * kp[2]
                + q3 * kp[3] + q4 * kp[4] + q5 * kp[5];
        }
        float s = dot + srpb[h * 27 + i * 9 + j * 3 + l];
        sc[i * 9 + j * 3 + l] = s;
        mx = fmaxf(mx, s);
    }

    float den = 0.0f;
    float pi0 = 0, pi2 = 0, pj0 = 0, pj2 = 0, pl0 = 0, pl2 = 0;
    #pragma unroll
    for (int i = 0; i < 3; ++i)
    #pragma unroll
    for (int j = 0; j < 3; ++j)
    #pragma unroll
    for (int l = 0; l < 3; ++l) {
        float e = __expf(sc[i * 9 + j * 3 + l] - mx);
        den += e;
        if (i == 0) pi0 += e; else if (i == 2) pi2 += e;
        if (j == 0) pj0 += e; else if (j == 2) pj2 += e;
        if (l == 0) pl0 += e; else if (l == 2) pl2 += e;
    }
    float inv = 1.0f / den;
    float ox = (pi2 - pi0) * inv;
    float oy = (pj2 - pj0) * inv;
    float oz = (pl2 - pl0) * inv;

    float* op = out + (size_t)(h * 3) * NVOX + vox;
    op[0]        = ox;
    op[NVOX]     = oy;
    op[2 * NVOX] = oz;
}

extern "C" void kernel_launch(void* const* d_in, const int* in_sizes, int n_in,
                              void* d_out, int out_size, void* d_ws, size_t ws_size,
                              hipStream_t stream) {
    const float* q   = (const float*)d_in[0];
    const float* k   = (const float*)d_in[1];
    const float* rpb = (const float*)d_in[2];
    float* out = (float*)d_out;

    int total = NVOX * NHE;              // 512000 threads, one per (voxel, head)
    int block = 256;
    int grid  = (total + block - 1) / block;  // 2000
    natt_kernel<<<grid, block, 0, stream>>>(q, k, rpb, out);
}